// Round 8
// baseline (240.667 us; speedup 1.0000x reference)
//
#include <hip/hip_runtime.h>

#define DMODEL 512
#define EPS_IN 1e-4f
#define EPS_LN 1e-5f
#define CLIPV  5.0f

typedef float f32x4 __attribute__((ext_vector_type(4)));
typedef short s16x8 __attribute__((ext_vector_type(8)));

__device__ __forceinline__ unsigned short f2bf(float f) {
    union { float f; unsigned u; } v; v.f = f;
    unsigned r = v.u + 0x7fffu + ((v.u >> 16) & 1u);
    return (unsigned short)(r >> 16);
}

struct TypeParams {
    const float* x;
    const float* ss;                   // scale[F] then shift[F]
    const unsigned short* Wt;          // [512][KP] bf16, zero-padded K
    const float* b; const float* gamma; const float* beta;
    int n;        // rows of this type
    int offset;   // row offset in concat order
    int nb;       // blocks (16-row tiles)
};

// Parts: [A] inv + tbatch/etype, [B] W -> Wt bf16 transpose, [C] scale/shift
__global__ __launch_bounds__(256) void setup_all(
    const int* __restrict__ index_map, const int* __restrict__ batch_index,
    int* __restrict__ inv, float* __restrict__ out_t, float* __restrict__ out_e,
    int total, int n0, int n01, int nbA,
    const float* __restrict__ W0, const float* __restrict__ W1, const float* __restrict__ W2,
    unsigned short* __restrict__ Wt0, unsigned short* __restrict__ Wt1, unsigned short* __restrict__ Wt2,
    const float* __restrict__ mean0, const float* __restrict__ var0,
    const float* __restrict__ mean1, const float* __restrict__ var1,
    const float* __restrict__ mean2, const float* __restrict__ var2,
    float* __restrict__ ss0, float* __restrict__ ss1, float* __restrict__ ss2)
{
    const int nbB = (DMODEL * 256) / 256;
    if (blockIdx.x < (unsigned)nbA) {
        const int j = blockIdx.x * 256 + threadIdx.x;
        if (j >= total) return;
        const int r = index_map[j];
        inv[r] = j;
        out_t[j] = (float)batch_index[r];
        out_e[j] = (r < n0) ? 0.0f : ((r < n01) ? 1.0f : 2.0f);
    } else if (blockIdx.x < (unsigned)(nbA + nbB)) {
        int idx = (blockIdx.x - nbA) * 256 + threadIdx.x;
        const float* W; unsigned short* Wt; int K, Kp;
        if (idx < DMODEL * 64)              { W = W0; Wt = Wt0; K = 64;  Kp = 64; }
        else if (idx < DMODEL * (64 + 128)) { idx -= DMODEL * 64;  W = W1; Wt = Wt1; K = 128; Kp = 128; }
        else                                { idx -= DMODEL * 192; W = W2; Wt = Wt2; K = 48;  Kp = 64; }
        const int nn = idx / Kp, k = idx - nn * Kp;
        const float w = (k < K) ? W[(size_t)k * DMODEL + nn] : 0.0f;
        Wt[idx] = f2bf(w);
    } else {
        const int c = threadIdx.x;
        if (c < 64)  { const float s = rsqrtf(var0[c] + EPS_IN); ss0[c] = s; ss0[64 + c]  = -mean0[c] * s; }
        if (c < 128) { const float s = rsqrtf(var1[c] + EPS_IN); ss1[c] = s; ss1[128 + c] = -mean1[c] * s; }
        if (c < 48)  { const float s = rsqrtf(var2[c] + EPS_IN); ss2[c] = s; ss2[48 + c]  = -mean2[c] * s; }
    }
}

// Block: 16 concat rows x 512 cols, 4 waves (wn = 128-col slice each).
// OPERAND-SWAPPED MFMA, per lane: xrow = lane&15, outcol = wn*128 + t*16 + 4g + j.
// LDS A layout: fragment-contiguous 16B units A[(ks*4+g)*16 + row] -> stage
// writes are linear tid*16; fragment reads are 16 consecutive 16B units.
template<int F, int KP>
__device__ __forceinline__ void embed_body(
    const TypeParams& p, int tile, const int* __restrict__ inv,
    float* __restrict__ out, char* lds)
{
    constexpr int SEG = KP / 8;   // 16B segments per row (8 or 16)
    constexpr int NKS = KP / 32;
    const int tid  = threadIdx.x;
    const int lane = tid & 63;
    const int wn   = tid >> 6;     // 0..3 (128-col slice)
    const int l15  = lane & 15;
    const int g    = lane >> 4;    // 0..3
    const int row0 = tile * 16;
    const int n    = p.n;

    float2* red = reinterpret_cast<float2*>(lds + 16 * KP * 2);  // [16 rows][4 wn]

    // ---- stage: InputNorm(x) -> bf16, fragment-order LDS (linear write)
    if (tid < 16 * SEG) {
        const int r = tid & 15;            // row within tile
        const int scol = (tid >> 4) * 8;   // col base
        const int gr = row0 + r;
        s16x8 pk;
#pragma unroll
        for (int jj = 0; jj < 8; ++jj) pk[jj] = 0;
        if (gr < n && scol < F) {
            const float4 x0 = *(const float4*)(p.x + (size_t)gr * F + scol);
            const float4 x1 = *(const float4*)(p.x + (size_t)gr * F + scol + 4);
            const float4 sc0 = *(const float4*)(p.ss + scol);
            const float4 sc1 = *(const float4*)(p.ss + scol + 4);
            const float4 sh0 = *(const float4*)(p.ss + F + scol);
            const float4 sh1 = *(const float4*)(p.ss + F + scol + 4);
            float t[8];
            t[0] = fmaf(x0.x, sc0.x, sh0.x); t[1] = fmaf(x0.y, sc0.y, sh0.y);
            t[2] = fmaf(x0.z, sc0.z, sh0.z); t[3] = fmaf(x0.w, sc0.w, sh0.w);
            t[4] = fmaf(x1.x, sc1.x, sh1.x); t[5] = fmaf(x1.y, sc1.y, sh1.y);
            t[6] = fmaf(x1.z, sc1.z, sh1.z); t[7] = fmaf(x1.w, sc1.w, sh1.w);
#pragma unroll
            for (int jj = 0; jj < 8; ++jj)
                pk[jj] = (short)f2bf(fminf(fmaxf(t[jj], -CLIPV), CLIPV));
        }
        *reinterpret_cast<s16x8*>(lds + tid * 16) = pk;
    }
    __syncthreads();

    // ---- prefetch inv for this lane's row (hidden behind MFMA)
    const int rg = row0 + l15;
    const int od = (rg < n) ? inv[p.offset + rg] : -1;

    // ---- MFMA (operand-swapped): acc[t], t over 8 col-tiles of 16
    f32x4 acc[8];
#pragma unroll
    for (int t = 0; t < 8; ++t) acc[t] = (f32x4)0.0f;

    const unsigned short* wtl = p.Wt + (size_t)(wn * 128 + l15) * KP + g * 8;

#pragma unroll
    for (int ks = 0; ks < NKS; ++ks) {
        const s16x8 a = *reinterpret_cast<const s16x8*>(lds + (ks * 4 + g) * 256 + l15 * 16);
#pragma unroll
        for (int t = 0; t < 8; ++t) {
            const s16x8 wf = *reinterpret_cast<const s16x8*>(wtl + (size_t)t * 16 * KP + ks * 32);
            acc[t] = __builtin_amdgcn_mfma_f32_16x16x32_bf16(wf, a, acc[t], 0, 0, 0);
        }
    }

    // ---- bias + ReLU in place
#pragma unroll
    for (int t = 0; t < 8; ++t) {
        const float4 bb = *(const float4*)(p.b + wn * 128 + t * 16 + g * 4);
        acc[t][0] = fmaxf(acc[t][0] + bb.x, 0.0f);
        acc[t][1] = fmaxf(acc[t][1] + bb.y, 0.0f);
        acc[t][2] = fmaxf(acc[t][2] + bb.z, 0.0f);
        acc[t][3] = fmaxf(acc[t][3] + bb.w, 0.0f);
    }

    // ---- LN partials: per lane 1 row x 32 cols; g-reduce (2 shuffles); cross-wave via red
    {
        float ps = 0.0f, pq = 0.0f;
#pragma unroll
        for (int t = 0; t < 8; ++t)
#pragma unroll
            for (int j = 0; j < 4; ++j) {
                const float v = acc[t][j];
                ps += v;
                pq = fmaf(v, v, pq);
            }
        ps += __shfl_xor(ps, 16, 64);
        pq += __shfl_xor(pq, 16, 64);
        ps += __shfl_xor(ps, 32, 64);
        pq += __shfl_xor(pq, 32, 64);
        if (g == 0) red[l15 * 4 + wn] = make_float2(ps, pq);
    }
    __syncthreads();

    // ---- finish LN + float4 scatter stores (1 row x 8 float4 per lane)
    if (od >= 0) {
        float s = 0.0f, q = 0.0f;
#pragma unroll
        for (int wq = 0; wq < 4; ++wq) { const float2 e = red[l15 * 4 + wq]; s += e.x; q += e.y; }
        const float mu = s * (1.0f / DMODEL);
        const float vv = fmaxf(q * (1.0f / DMODEL) - mu * mu, 0.0f);
        const float sc = rsqrtf(vv + EPS_LN);
        float* op = out + (size_t)od * DMODEL + wn * 128 + g * 4;
#pragma unroll
        for (int t = 0; t < 8; ++t) {
            const float4 gg = *(const float4*)(p.gamma + wn * 128 + t * 16 + g * 4);
            const float4 ee = *(const float4*)(p.beta  + wn * 128 + t * 16 + g * 4);
            float4 o;
            o.x = fmaf(gg.x * sc, acc[t][0] - mu, ee.x);
            o.y = fmaf(gg.y * sc, acc[t][1] - mu, ee.y);
            o.z = fmaf(gg.z * sc, acc[t][2] - mu, ee.z);
            o.w = fmaf(gg.w * sc, acc[t][3] - mu, ee.w);
            *(float4*)(op + t * 16) = o;
        }
    }
}

__global__ __launch_bounds__(256, 5) void embed_all(
    TypeParams p0, TypeParams p1, TypeParams p2,
    const int* __restrict__ inv, float* __restrict__ out)
{
    extern __shared__ char lds[];
    const int bid = blockIdx.x;
    if (bid < p0.nb)                embed_body<64, 64>  (p0, bid, inv, out, lds);
    else if (bid < p0.nb + p1.nb)   embed_body<128, 128>(p1, bid - p0.nb, inv, out, lds);
    else                            embed_body<48, 64>  (p2, bid - p0.nb - p1.nb, inv, out, lds);
}

extern "C" void kernel_launch(void* const* d_in, const int* in_sizes, int n_in,
                              void* d_out, int out_size, void* d_ws, size_t ws_size,
                              hipStream_t stream)
{
    const int F0 = 64, F1 = 128, F2 = 48;
    const int n0 = in_sizes[0]  / F0;
    const int n1 = in_sizes[7]  / F1;
    const int n2 = in_sizes[14] / F2;
    const int total = n0 + n1 + n2;

    float* out   = (float*)d_out;
    float* out_t = out + (size_t)total * DMODEL;
    float* out_e = out_t + total;

    // ws layout: inv[total] ints | Wt0/Wt1/Wt2 bf16 | ss0/ss1/ss2 f32
    int* inv = (int*)d_ws;
    unsigned short* Wt0 = (unsigned short*)((char*)d_ws + (((size_t)total * 4 + 255) & ~(size_t)255));
    unsigned short* Wt1 = Wt0 + DMODEL * 64;
    unsigned short* Wt2 = Wt1 + DMODEL * 128;
    float* ss0 = (float*)(Wt2 + DMODEL * 64);
    float* ss1 = ss0 + 128;
    float* ss2 = ss1 + 256;

    const int* index_map   = (const int*)d_in[21];
    const int* batch_index = (const int*)d_in[22];

    const int nbA = (total + 255) / 256;
    const int nbB = (DMODEL * 256) / 256;
    setup_all<<<nbA + nbB + 1, 256, 0, stream>>>(
        index_map, batch_index, inv, out_t, out_e, total, n0, n0 + n1, nbA,
        (const float*)d_in[3], (const float*)d_in[10], (const float*)d_in[17],
        Wt0, Wt1, Wt2,
        (const float*)d_in[1],  (const float*)d_in[2],
        (const float*)d_in[8],  (const float*)d_in[9],
        (const float*)d_in[15], (const float*)d_in[16],
        ss0, ss1, ss2);

    TypeParams p0{(const float*)d_in[0],  ss0, Wt0,
                  (const float*)d_in[4],  (const float*)d_in[5],  (const float*)d_in[6],
                  n0, 0,       (n0 + 15) / 16};
    TypeParams p1{(const float*)d_in[7],  ss1, Wt1,
                  (const float*)d_in[11], (const float*)d_in[12], (const float*)d_in[13],
                  n1, n0,      (n1 + 15) / 16};
    TypeParams p2{(const float*)d_in[14], ss2, Wt2,
                  (const float*)d_in[18], (const float*)d_in[19], (const float*)d_in[20],
                  n2, n0 + n1, (n2 + 15) / 16};

    const int nb = p0.nb + p1.nb + p2.nb;
    const int lds_size = 16 * 128 * 2 + 16 * 4 * sizeof(float2);  // 4224 B
    embed_all<<<nb, 256, lds_size, stream>>>(p0, p1, p2, inv, out);
}

// Round 9
// 179.396 us; speedup vs baseline: 1.3415x; 1.3415x over previous
//
#include <hip/hip_runtime.h>

#define DMODEL 512
#define EPS_IN 1e-4f
#define EPS_LN 1e-5f
#define CLIPV  5.0f

typedef float f32x4 __attribute__((ext_vector_type(4)));
typedef short s16x8 __attribute__((ext_vector_type(8)));

__device__ __forceinline__ unsigned short f2bf(float f) {
    union { float f; unsigned u; } v; v.f = f;
    unsigned r = v.u + 0x7fffu + ((v.u >> 16) & 1u);
    return (unsigned short)(r >> 16);
}

__device__ __forceinline__ void gload16(const void* g, void* l) {
    __builtin_amdgcn_global_load_lds(
        (const __attribute__((address_space(1))) unsigned int*)g,
        (__attribute__((address_space(3))) unsigned int*)l, 16, 0, 0);
}

// ======================= PACKED PATH =======================
// A_packed tile layout (32 rows x KP cols bf16, tile = KP*64 bytes):
//   element (r, s)  [s = 8-col segment]  ->  byte offset
//   off = (s>>2)*2048 + (r>>4)*1024 + (((s&3)*16 + (r&15)) << 4)
// so the MFMA A-fragment read is lds[ks*2048 + m*1024 + lane*16]:
// 64 lanes x 16B contiguous -> conflict-free; global_load_lds stage is linear.

struct PackArgs {
    const float* x; const float* mean; const float* var;
    char* Ap;
    int n, F, SEG, KP, nblocks;
};

__device__ __forceinline__ void pack_tile(const PackArgs& q, int lb) {
    const int idx = lb * 256 + threadIdx.x;
    int s, rg;
    if (q.SEG == 8) { s = idx & 7;  rg = idx >> 3; }
    else            { s = idx & 15; rg = idx >> 4; }
    const int c = s * 8;
    s16x8 pk;
#pragma unroll
    for (int j = 0; j < 8; ++j) pk[j] = 0;
    if (rg < q.n && c < q.F) {
        const float4 x0 = *(const float4*)(q.x + (size_t)rg * q.F + c);
        const float4 x1 = *(const float4*)(q.x + (size_t)rg * q.F + c + 4);
        const float4 m0 = *(const float4*)(q.mean + c);
        const float4 m1 = *(const float4*)(q.mean + c + 4);
        const float4 v0 = *(const float4*)(q.var + c);
        const float4 v1 = *(const float4*)(q.var + c + 4);
        float t[8];
        t[0] = (x0.x - m0.x) * rsqrtf(v0.x + EPS_IN);
        t[1] = (x0.y - m0.y) * rsqrtf(v0.y + EPS_IN);
        t[2] = (x0.z - m0.z) * rsqrtf(v0.z + EPS_IN);
        t[3] = (x0.w - m0.w) * rsqrtf(v0.w + EPS_IN);
        t[4] = (x1.x - m1.x) * rsqrtf(v1.x + EPS_IN);
        t[5] = (x1.y - m1.y) * rsqrtf(v1.y + EPS_IN);
        t[6] = (x1.z - m1.z) * rsqrtf(v1.z + EPS_IN);
        t[7] = (x1.w - m1.w) * rsqrtf(v1.w + EPS_IN);
#pragma unroll
        for (int j = 0; j < 8; ++j)
            pk[j] = (short)f2bf(fminf(fmaxf(t[j], -CLIPV), CLIPV));
    }
    const int r = rg & 31, tile = rg >> 5;
    const int off = (s >> 2) * 2048 + ((r >> 4) << 10) + (((s & 3) * 16 + (r & 15)) << 4);
    *(s16x8*)(q.Ap + (size_t)tile * (q.KP * 64) + off) = pk;
}

__global__ __launch_bounds__(256) void prep_packed(
    const int* __restrict__ index_map, const int* __restrict__ batch_index,
    int* __restrict__ inv, float* __restrict__ out_t, float* __restrict__ out_e,
    int total, int n0, int n01, int nbA,
    const float* __restrict__ W0, const float* __restrict__ W1, const float* __restrict__ W2,
    unsigned short* __restrict__ Wt0, unsigned short* __restrict__ Wt1, unsigned short* __restrict__ Wt2,
    PackArgs q0, PackArgs q1, PackArgs q2)
{
    int b = blockIdx.x;
    if (b < nbA) {
        const int j = b * 256 + threadIdx.x;
        if (j >= total) return;
        const int r = index_map[j];
        inv[r] = j;
        out_t[j] = (float)batch_index[r];
        out_e[j] = (r < n0) ? 0.0f : ((r < n01) ? 1.0f : 2.0f);
        return;
    }
    b -= nbA;
    if (b < 512) {
        int idx = b * 256 + threadIdx.x;
        const float* W; unsigned short* Wt; int K, Kp;
        if (idx < DMODEL * 64)              { W = W0; Wt = Wt0; K = 64;  Kp = 64; }
        else if (idx < DMODEL * (64 + 128)) { idx -= DMODEL * 64;  W = W1; Wt = Wt1; K = 128; Kp = 128; }
        else                                { idx -= DMODEL * 192; W = W2; Wt = Wt2; K = 48;  Kp = 64; }
        const int nn = idx / Kp, k = idx - nn * Kp;
        const float w = (k < K) ? W[(size_t)k * DMODEL + nn] : 0.0f;
        Wt[idx] = f2bf(w);
        return;
    }
    b -= 512;
    if (b < q0.nblocks) { pack_tile(q0, b); return; }
    b -= q0.nblocks;
    if (b < q1.nblocks) { pack_tile(q1, b); return; }
    b -= q1.nblocks;
    pack_tile(q2, b);
}

struct TypeParamsP {
    const char* Ap;
    const unsigned short* Wt;
    const float* b; const float* gamma; const float* beta;
    int n, offset, nb;   // nb = 32-row tiles
};

// Block: 32 rows x 512 cols, 8 waves, wave = 32 rows x 64 cols (wn).
// Stage: 1 global_load_lds_dwordx4 per thread (tile is pre-packed, pre-normalized).
template<int KP>
__device__ __forceinline__ void embed_body_p(
    const TypeParamsP& p, int tile, const int* __restrict__ inv,
    float* __restrict__ out, char* lds)
{
    constexpr int NKS = KP / 32;
    constexpr int TB  = KP * 64;
    const int tid  = threadIdx.x;
    const int lane = tid & 63;
    const int wn   = tid >> 6;
    const int l15  = lane & 15;
    const int g    = lane >> 4;
    const int n    = p.n;

    float2* red = reinterpret_cast<float2*>(lds + 8192);

    // ---- DMA stage: tile bytes -> LDS linearly (wave w covers [w*1KB, w*1KB+1KB))
    const char* src = p.Ap + (size_t)tile * TB;
    if (KP == 128) {
        gload16(src + tid * 16, lds + (tid >> 6) * 1024);
    } else {
        if (tid < 256) gload16(src + tid * 16, lds + (tid >> 6) * 1024);
    }

    // ---- inv prefetch (independent of LDS)
    int orow[2];
#pragma unroll
    for (int m = 0; m < 2; ++m) {
        const int rg = tile * 32 + m * 16 + l15;
        orow[m] = (rg < n) ? inv[p.offset + rg] : -1;
    }
    __syncthreads();

    // ---- MFMA (operand-swapped): per lane xrow = m*16+l15, outcol = wn*64+t*16+4g+j
    f32x4 acc[2][4];
#pragma unroll
    for (int m = 0; m < 2; ++m)
#pragma unroll
        for (int t = 0; t < 4; ++t) acc[m][t] = (f32x4)0.0f;

    const unsigned short* wtl = p.Wt + (size_t)(wn * 64 + l15) * KP + g * 8;

#pragma unroll
    for (int ks = 0; ks < NKS; ++ks) {
        const s16x8 a0 = *reinterpret_cast<const s16x8*>(lds + ks * 2048 + lane * 16);
        const s16x8 a1 = *reinterpret_cast<const s16x8*>(lds + ks * 2048 + 1024 + lane * 16);
#pragma unroll
        for (int t = 0; t < 4; ++t) {
            const s16x8 wf = *reinterpret_cast<const s16x8*>(wtl + (size_t)t * 16 * KP + ks * 32);
            acc[0][t] = __builtin_amdgcn_mfma_f32_16x16x32_bf16(wf, a0, acc[0][t], 0, 0, 0);
            acc[1][t] = __builtin_amdgcn_mfma_f32_16x16x32_bf16(wf, a1, acc[1][t], 0, 0, 0);
        }
    }

    // ---- bias + ReLU
#pragma unroll
    for (int t = 0; t < 4; ++t) {
        const float4 bb = *(const float4*)(p.b + wn * 64 + t * 16 + g * 4);
#pragma unroll
        for (int m = 0; m < 2; ++m) {
            acc[m][t][0] = fmaxf(acc[m][t][0] + bb.x, 0.0f);
            acc[m][t][1] = fmaxf(acc[m][t][1] + bb.y, 0.0f);
            acc[m][t][2] = fmaxf(acc[m][t][2] + bb.z, 0.0f);
            acc[m][t][3] = fmaxf(acc[m][t][3] + bb.w, 0.0f);
        }
    }

    // ---- LN partials
    {
        float ps[2] = {0.0f, 0.0f}, pq[2] = {0.0f, 0.0f};
#pragma unroll
        for (int m = 0; m < 2; ++m)
#pragma unroll
            for (int t = 0; t < 4; ++t)
#pragma unroll
                for (int j = 0; j < 4; ++j) {
                    const float v = acc[m][t][j];
                    ps[m] += v;
                    pq[m] = fmaf(v, v, pq[m]);
                }
#pragma unroll
        for (int m = 0; m < 2; ++m) {
            ps[m] += __shfl_xor(ps[m], 16, 64);
            pq[m] += __shfl_xor(pq[m], 16, 64);
            ps[m] += __shfl_xor(ps[m], 32, 64);
            pq[m] += __shfl_xor(pq[m], 32, 64);
        }
        if (g == 0) {
#pragma unroll
            for (int m = 0; m < 2; ++m)
                red[(m * 16 + l15) * 8 + wn] = make_float2(ps[m], pq[m]);
        }
    }
    __syncthreads();

    // ---- finish LN + float4 scatter stores
#pragma unroll
    for (int m = 0; m < 2; ++m) {
        const int od = orow[m];
        if (od < 0) continue;
        const int rl = m * 16 + l15;
        float s = 0.0f, q = 0.0f;
#pragma unroll
        for (int wq = 0; wq < 8; ++wq) { const float2 e = red[rl * 8 + wq]; s += e.x; q += e.y; }
        const float mu = s * (1.0f / DMODEL);
        const float vv = fmaxf(q * (1.0f / DMODEL) - mu * mu, 0.0f);
        const float sc = rsqrtf(vv + EPS_LN);
        float* op = out + (size_t)od * DMODEL + wn * 64 + g * 4;
#pragma unroll
        for (int t = 0; t < 4; ++t) {
            const float4 gg = *(const float4*)(p.gamma + wn * 64 + t * 16 + g * 4);
            const float4 ee = *(const float4*)(p.beta  + wn * 64 + t * 16 + g * 4);
            float4 o;
            o.x = fmaf(gg.x * sc, acc[m][t][0] - mu, ee.x);
            o.y = fmaf(gg.y * sc, acc[m][t][1] - mu, ee.y);
            o.z = fmaf(gg.z * sc, acc[m][t][2] - mu, ee.z);
            o.w = fmaf(gg.w * sc, acc[m][t][3] - mu, ee.w);
            *(float4*)(op + t * 16) = o;
        }
    }
}

__global__ __launch_bounds__(512, 5) void embed_packed(
    TypeParamsP p0, TypeParamsP p1, TypeParamsP p2,
    const int* __restrict__ inv, float* __restrict__ out)
{
    __shared__ char lds[8192 + 32 * 8 * sizeof(float2)];
    const int bid = blockIdx.x;
    if (bid < p0.nb)                embed_body_p<64> (p0, bid, inv, out, lds);
    else if (bid < p0.nb + p1.nb)   embed_body_p<128>(p1, bid - p0.nb, inv, out, lds);
    else                            embed_body_p<64> (p2, bid - p0.nb - p1.nb, inv, out, lds);
}

// ======================= FALLBACK PATH (round-5, 161 us) =======================

struct TypeParams {
    const float* x; const float* ss; const unsigned short* Wt;
    const float* b; const float* gamma; const float* beta;
    int n, offset, nb;
};

__global__ __launch_bounds__(256) void setup_fb(
    const int* __restrict__ index_map, const int* __restrict__ batch_index,
    int* __restrict__ inv, float* __restrict__ out_t, float* __restrict__ out_e,
    int total, int n0, int n01, int nbA,
    const float* __restrict__ W0, const float* __restrict__ W1, const float* __restrict__ W2,
    unsigned short* __restrict__ Wt0, unsigned short* __restrict__ Wt1, unsigned short* __restrict__ Wt2,
    const float* __restrict__ mean0, const float* __restrict__ var0,
    const float* __restrict__ mean1, const float* __restrict__ var1,
    const float* __restrict__ mean2, const float* __restrict__ var2,
    float* __restrict__ ss0, float* __restrict__ ss1, float* __restrict__ ss2)
{
    if (blockIdx.x < (unsigned)nbA) {
        const int j = blockIdx.x * 256 + threadIdx.x;
        if (j >= total) return;
        const int r = index_map[j];
        inv[r] = j;
        out_t[j] = (float)batch_index[r];
        out_e[j] = (r < n0) ? 0.0f : ((r < n01) ? 1.0f : 2.0f);
    } else if (blockIdx.x < (unsigned)(nbA + 512)) {
        int idx = (blockIdx.x - nbA) * 256 + threadIdx.x;
        const float* W; unsigned short* Wt; int K, Kp;
        if (idx < DMODEL * 64)              { W = W0; Wt = Wt0; K = 64;  Kp = 64; }
        else if (idx < DMODEL * (64 + 128)) { idx -= DMODEL * 64;  W = W1; Wt = Wt1; K = 128; Kp = 128; }
        else                                { idx -= DMODEL * 192; W = W2; Wt = Wt2; K = 48;  Kp = 64; }
        const int nn = idx / Kp, k = idx - nn * Kp;
        const float w = (k < K) ? W[(size_t)k * DMODEL + nn] : 0.0f;
        Wt[idx] = f2bf(w);
    } else {
        const int c = threadIdx.x;
        if (c < 64)  { const float s = rsqrtf(var0[c] + EPS_IN); ss0[c] = s; ss0[64 + c]  = -mean0[c] * s; }
        if (c < 128) { const float s = rsqrtf(var1[c] + EPS_IN); ss1[c] = s; ss1[128 + c] = -mean1[c] * s; }
        if (c < 48)  { const float s = rsqrtf(var2[c] + EPS_IN); ss2[c] = s; ss2[48 + c]  = -mean2[c] * s; }
    }
}

template<int F, int KP>
__device__ __forceinline__ void embed_body_fb(
    const TypeParams& p, int bid, const int* __restrict__ inv,
    float* __restrict__ out, char* lds)
{
    constexpr int SEG = KP / 8;
    constexpr int NKS = KP / 32;
    const int tid  = threadIdx.x;
    const int lane = tid & 63;
    const int wn   = tid >> 6;
    const int l15  = lane & 15;
    const int g    = lane >> 4;
    const int row0 = bid * 32;
    const int n    = p.n;

    float2* red = reinterpret_cast<float2*>(lds + NKS * 2048);

    if (tid < 32 * SEG) {
        const int r = tid & 31;
        const int s = tid >> 5;
        const int c = s * 8;
        const int gr = row0 + r;
        s16x8 pk;
#pragma unroll
        for (int jj = 0; jj < 8; ++jj) pk[jj] = 0;
        if (gr < n && c < F) {
            const float4 x0 = *(const float4*)(p.x + (size_t)gr * F + c);
            const float4 x1 = *(const float4*)(p.x + (size_t)gr * F + c + 4);
            const float4 sc0 = *(const float4*)(p.ss + c);
            const float4 sc1 = *(const float4*)(p.ss + c + 4);
            const float4 sh0 = *(const float4*)(p.ss + F + c);
            const float4 sh1 = *(const float4*)(p.ss + F + c + 4);
            float t[8];
            t[0] = fmaf(x0.x, sc0.x, sh0.x); t[1] = fmaf(x0.y, sc0.y, sh0.y);
            t[2] = fmaf(x0.z, sc0.z, sh0.z); t[3] = fmaf(x0.w, sc0.w, sh0.w);
            t[4] = fmaf(x1.x, sc1.x, sh1.x); t[5] = fmaf(x1.y, sc1.y, sh1.y);
            t[6] = fmaf(x1.z, sc1.z, sh1.z); t[7] = fmaf(x1.w, sc1.w, sh1.w);
#pragma unroll
            for (int jj = 0; jj < 8; ++jj)
                pk[jj] = (short)f2bf(fminf(fmaxf(t[jj], -CLIPV), CLIPV));
        }
        *reinterpret_cast<s16x8*>(lds + tid * 16) = pk;
    }
    __syncthreads();

    int orow[2];
#pragma unroll
    for (int m = 0; m < 2; ++m) {
        const int rg = row0 + m * 16 + l15;
        orow[m] = (rg < n) ? inv[p.offset + rg] : -1;
    }

    f32x4 acc[2][4];
#pragma unroll
    for (int m = 0; m < 2; ++m)
#pragma unroll
        for (int t = 0; t < 4; ++t) acc[m][t] = (f32x4)0.0f;

    const unsigned short* wtl = p.Wt + (size_t)(wn * 64 + l15) * KP + g * 8;

#pragma unroll
    for (int ks = 0; ks < NKS; ++ks) {
        const int ab = ((ks * 4 + g) * 32 + l15) * 16;
        const s16x8 a0 = *reinterpret_cast<const s16x8*>(lds + ab);
        const s16x8 a1 = *reinterpret_cast<const s16x8*>(lds + ab + 256);
#pragma unroll
        for (int t = 0; t < 4; ++t) {
            const s16x8 wf = *reinterpret_cast<const s16x8*>(wtl + (size_t)t * 16 * KP + ks * 32);
            acc[0][t] = __builtin_amdgcn_mfma_f32_16x16x32_bf16(wf, a0, acc[0][t], 0, 0, 0);
            acc[1][t] = __builtin_amdgcn_mfma_f32_16x16x32_bf16(wf, a1, acc[1][t], 0, 0, 0);
        }
    }

#pragma unroll
    for (int t = 0; t < 4; ++t) {
        const float4 bb = *(const float4*)(p.b + wn * 64 + t * 16 + g * 4);
#pragma unroll
        for (int m = 0; m < 2; ++m) {
            acc[m][t][0] = fmaxf(acc[m][t][0] + bb.x, 0.0f);
            acc[m][t][1] = fmaxf(acc[m][t][1] + bb.y, 0.0f);
            acc[m][t][2] = fmaxf(acc[m][t][2] + bb.z, 0.0f);
            acc[m][t][3] = fmaxf(acc[m][t][3] + bb.w, 0.0f);
        }
    }

    {
        float ps[2] = {0.0f, 0.0f}, pq[2] = {0.0f, 0.0f};
#pragma unroll
        for (int m = 0; m < 2; ++m)
#pragma unroll
            for (int t = 0; t < 4; ++t)
#pragma unroll
                for (int j = 0; j < 4; ++j) {
                    const float v = acc[m][t][j];
                    ps[m] += v;
                    pq[m] = fmaf(v, v, pq[m]);
                }
#pragma unroll
        for (int m = 0; m < 2; ++m) {
            ps[m] += __shfl_xor(ps[m], 16, 64);
            pq[m] += __shfl_xor(pq[m], 16, 64);
            ps[m] += __shfl_xor(ps[m], 32, 64);
            pq[m] += __shfl_xor(pq[m], 32, 64);
        }
        if (g == 0) {
#pragma unroll
            for (int m = 0; m < 2; ++m)
                red[(m * 16 + l15) * 8 + wn] = make_float2(ps[m], pq[m]);
        }
    }
    __syncthreads();

#pragma unroll
    for (int m = 0; m < 2; ++m) {
        const int od = orow[m];
        if (od < 0) continue;
        const int rl = m * 16 + l15;
        float s = 0.0f, q = 0.0f;
#pragma unroll
        for (int wq = 0; wq < 8; ++wq) { const float2 e = red[rl * 8 + wq]; s += e.x; q += e.y; }
        const float mu = s * (1.0f / DMODEL);
        const float vv = fmaxf(q * (1.0f / DMODEL) - mu * mu, 0.0f);
        const float sc = rsqrtf(vv + EPS_LN);
        float* op = out + (size_t)od * DMODEL + wn * 64 + g * 4;
#pragma unroll
        for (int t = 0; t < 4; ++t) {
            const float4 gg = *(const float4*)(p.gamma + wn * 64 + t * 16 + g * 4);
            const float4 ee = *(const float4*)(p.beta  + wn * 64 + t * 16 + g * 4);
            float4 o;
            o.x = fmaf(gg.x * sc, acc[m][t][0] - mu, ee.x);
            o.y = fmaf(gg.y * sc, acc[m][t][1] - mu, ee.y);
            o.z = fmaf(gg.z * sc, acc[m][t][2] - mu, ee.z);
            o.w = fmaf(gg.w * sc, acc[m][t][3] - mu, ee.w);
            *(float4*)(op + t * 16) = o;
        }
    }
}

__global__ __launch_bounds__(512, 4) void embed_fb(
    TypeParams p0, TypeParams p1, TypeParams p2,
    const int* __restrict__ inv, float* __restrict__ out)
{
    extern __shared__ char lds[];
    const int bid = blockIdx.x;
    if (bid < p0.nb)                embed_body_fb<64, 64>  (p0, bid, inv, out, lds);
    else if (bid < p0.nb + p1.nb)   embed_body_fb<128, 128>(p1, bid - p0.nb, inv, out, lds);
    else                            embed_body_fb<48, 64>  (p2, bid - p0.nb - p1.nb, inv, out, lds);
}

// ======================= HOST =======================

extern "C" void kernel_launch(void* const* d_in, const int* in_sizes, int n_in,
                              void* d_out, int out_size, void* d_ws, size_t ws_size,
                              hipStream_t stream)
{
    const int F0 = 64, F1 = 128, F2 = 48;
    const int n0 = in_sizes[0]  / F0;
    const int n1 = in_sizes[7]  / F1;
    const int n2 = in_sizes[14] / F2;
    const int total = n0 + n1 + n2;
    const int nt0 = (n0 + 31) / 32, nt1 = (n1 + 31) / 32, nt2 = (n2 + 31) / 32;

    float* out   = (float*)d_out;
    float* out_t = out + (size_t)total * DMODEL;
    float* out_e = out_t + total;

    // ws layout: inv | Wt0/Wt1/Wt2 | ss0/ss1/ss2 | A0 | A1 | A2
    int* inv = (int*)d_ws;
    size_t off = (((size_t)total * 4) + 255) & ~(size_t)255;
    unsigned short* Wt0 = (unsigned short*)((char*)d_ws + off);
    unsigned short* Wt1 = Wt0 + DMODEL * 64;
    unsigned short* Wt2 = Wt1 + DMODEL * 128;
    float* ss0 = (float*)(Wt2 + DMODEL * 64);
    float* ss1 = ss0 + 128;
    float* ss2 = ss1 + 256;
    size_t aoff = ((off + (size_t)DMODEL * 256 * 2 + 4096) + 255) & ~(size_t)255;
    char* A0 = (char*)d_ws + aoff;
    char* A1 = A0 + (size_t)nt0 * 4096;
    char* A2 = A1 + (size_t)nt1 * 8192;
    const size_t need = aoff + (size_t)nt0 * 4096 + (size_t)nt1 * 8192 + (size_t)nt2 * 4096;

    const int* index_map   = (const int*)d_in[21];
    const int* batch_index = (const int*)d_in[22];
    const int nbA = (total + 255) / 256;

    if (ws_size >= need) {
        // -------- packed path --------
        PackArgs q0{(const float*)d_in[0],  (const float*)d_in[1],  (const float*)d_in[2],
                    A0, n0, F0, 8,  64,  nt0};
        PackArgs q1{(const float*)d_in[7],  (const float*)d_in[8],  (const float*)d_in[9],
                    A1, n1, F1, 16, 128, nt1 * 2};
        PackArgs q2{(const float*)d_in[14], (const float*)d_in[15], (const float*)d_in[16],
                    A2, n2, F2, 8,  64,  nt2};

        const int nbP = nbA + 512 + q0.nblocks + q1.nblocks + q2.nblocks;
        prep_packed<<<nbP, 256, 0, stream>>>(
            index_map, batch_index, inv, out_t, out_e, total, n0, n0 + n1, nbA,
            (const float*)d_in[3], (const float*)d_in[10], (const float*)d_in[17],
            Wt0, Wt1, Wt2, q0, q1, q2);

        TypeParamsP p0{A0, Wt0, (const float*)d_in[4],  (const float*)d_in[5],  (const float*)d_in[6],
                       n0, 0,       nt0};
        TypeParamsP p1{A1, Wt1, (const float*)d_in[11], (const float*)d_in[12], (const float*)d_in[13],
                       n1, n0,      nt1};
        TypeParamsP p2{A2, Wt2, (const float*)d_in[18], (const float*)d_in[19], (const float*)d_in[20],
                       n2, n0 + n1, nt2};

        embed_packed<<<nt0 + nt1 + nt2, 512, 0, stream>>>(p0, p1, p2, inv, out);
    } else {
        // -------- fallback: round-5 --------
        setup_fb<<<nbA + 512 + 1, 256, 0, stream>>>(
            index_map, batch_index, inv, out_t, out_e, total, n0, n0 + n1, nbA,
            (const float*)d_in[3], (const float*)d_in[10], (const float*)d_in[17],
            Wt0, Wt1, Wt2,
            (const float*)d_in[1],  (const float*)d_in[2],
            (const float*)d_in[8],  (const float*)d_in[9],
            (const float*)d_in[15], (const float*)d_in[16],
            ss0, ss1, ss2);

        TypeParams p0{(const float*)d_in[0],  ss0, Wt0,
                      (const float*)d_in[4],  (const float*)d_in[5],  (const float*)d_in[6],
                      n0, 0,       nt0};
        TypeParams p1{(const float*)d_in[7],  ss1, Wt1,
                      (const float*)d_in[11], (const float*)d_in[12], (const float*)d_in[13],
                      n1, n0,      nt1};
        TypeParams p2{(const float*)d_in[14], ss2, Wt2,
                      (const float*)d_in[18], (const float*)d_in[19], (const float*)d_in[20],
                      n2, n0 + n1, nt2};

        const int lds_size = 4 * 2048 + 32 * 8 * sizeof(float2);
        embed_fb<<<nt0 + nt1 + nt2, 512, lds_size, stream>>>(p0, p1, p2, inv, out);
    }
}